// Round 1
// baseline (295.796 us; speedup 1.0000x reference)
//
#include <hip/hip_runtime.h>
#include <hip/hip_bf16.h>

#define BS   8192
#define DIM  768
#define TILE 128
#define BK   32

typedef __bf16 bf16x8 __attribute__((ext_vector_type(8)));
typedef float  f32x4  __attribute__((ext_vector_type(4)));

__device__ __forceinline__ void async16(const void* g, void* l) {
    __builtin_amdgcn_global_load_lds(
        (const __attribute__((address_space(1))) unsigned int*)g,
        (__attribute__((address_space(3))) unsigned int*)l,
        16, 0, 0);
}

// One block (256 thr) per row: L2-norm both embeddings, emit bf16, and the
// diagonal similarity S_ii in fp32.
__global__ __launch_bounds__(256) void normalize_kernel(
    const float* __restrict__ text, const float* __restrict__ ctr,
    __hip_bfloat16* __restrict__ tb, __hip_bfloat16* __restrict__ cb,
    float* __restrict__ sim) {
    const int row = blockIdx.x;
    const int tid = threadIdx.x;
    const size_t base = (size_t)row * DIM;

    float tx[3], cx[3];
    float st = 0.f, sc = 0.f, sd = 0.f;
#pragma unroll
    for (int i = 0; i < 3; ++i) {
        tx[i] = text[base + tid + 256 * i];
        cx[i] = ctr [base + tid + 256 * i];
        st += tx[i] * tx[i];
        sc += cx[i] * cx[i];
        sd += tx[i] * cx[i];
    }
#pragma unroll
    for (int off = 1; off < 64; off <<= 1) {
        st += __shfl_xor(st, off);
        sc += __shfl_xor(sc, off);
        sd += __shfl_xor(sd, off);
    }
    __shared__ float red[3][4];
    const int wave = tid >> 6, lane = tid & 63;
    if (lane == 0) { red[0][wave] = st; red[1][wave] = sc; red[2][wave] = sd; }
    __syncthreads();
    st = red[0][0] + red[0][1] + red[0][2] + red[0][3];
    sc = red[1][0] + red[1][1] + red[1][2] + red[1][3];
    sd = red[2][0] + red[2][1] + red[2][2] + red[2][3];

    const float invt = 1.0f / fmaxf(sqrtf(st), 1e-8f);
    const float invc = 1.0f / fmaxf(sqrtf(sc), 1e-8f);
#pragma unroll
    for (int i = 0; i < 3; ++i) {
        tb[base + tid + 256 * i] = __float2bfloat16(tx[i] * invt);
        cb[base + tid + 256 * i] = __float2bfloat16(cx[i] * invc);
    }
    if (tid == 0) sim[row] = sd * invt * invc;
}

// 128x128 tile, 4 waves in 2x2; each wave: 4x4 frags of 16x16x32 bf16 MFMA.
// Epilogue: exp() + reduce into global rowsum/colsum via atomics.
__global__ __launch_bounds__(256) void gemm_lse_kernel(
    const __hip_bfloat16* __restrict__ tbp, const __hip_bfloat16* __restrict__ cbp,
    float* __restrict__ rowsum, float* __restrict__ colsum) {
    __shared__ short ldsA[TILE * BK];   // 8 KB, row-major [128][32]
    __shared__ short ldsB[TILE * BK];   // 8 KB

    const int tid  = threadIdx.x;
    const int rowBase = blockIdx.y * TILE;
    const int colBase = blockIdx.x * TILE;
    const short* A = (const short*)tbp;
    const short* B = (const short*)cbp;

    const int wave = tid >> 6, lane = tid & 63;
    const int wr = wave >> 1, wc = wave & 1;        // 2x2 wave grid
    const int quad = lane >> 4, l16 = lane & 15;

    f32x4 acc[4][4];
#pragma unroll
    for (int mt = 0; mt < 4; ++mt)
#pragma unroll
        for (int nt = 0; nt < 4; ++nt)
            acc[mt][nt] = (f32x4){0.f, 0.f, 0.f, 0.f};

    for (int k0 = 0; k0 < DIM; k0 += BK) {
        // Stage A and B tiles: 512 chunks of 16B each; thread t does chunks t, t+256.
        // Chunk c -> row c>>2, k-offset (c&3)*8; LDS chunk order == row-major layout.
#pragma unroll
        for (int h = 0; h < 2; ++h) {
            const int c = tid + h * 256;
            const int r = c >> 2, kc = (c & 3) * 8;
            async16(A + (size_t)(rowBase + r) * DIM + k0 + kc, &ldsA[c * 8]);
            async16(B + (size_t)(colBase + r) * DIM + k0 + kc, &ldsB[c * 8]);
        }
        __syncthreads();   // compiler emits vmcnt(0) drain before s_barrier

        bf16x8 af[4], bfr[4];
#pragma unroll
        for (int mt = 0; mt < 4; ++mt)
            af[mt] = *(const bf16x8*)&ldsA[(wr * 64 + mt * 16 + l16) * BK + quad * 8];
#pragma unroll
        for (int nt = 0; nt < 4; ++nt)
            bfr[nt] = *(const bf16x8*)&ldsB[(wc * 64 + nt * 16 + l16) * BK + quad * 8];
#pragma unroll
        for (int mt = 0; mt < 4; ++mt)
#pragma unroll
            for (int nt = 0; nt < 4; ++nt)
                acc[mt][nt] = __builtin_amdgcn_mfma_f32_16x16x32_bf16(
                    af[mt], bfr[nt], acc[mt][nt], 0, 0, 0);
        __syncthreads();   // all reads done before next stage overwrites LDS
    }

    // Epilogue. D layout: col = l16 (ctr idx), row = quad*4 + reg (text idx).
    float rp[4][4];   // [mt][reg] partial row sums over this wave's 64 cols
    float cp[4];      // [nt] partial col sums over this wave's 64 rows
#pragma unroll
    for (int mt = 0; mt < 4; ++mt)
#pragma unroll
        for (int r = 0; r < 4; ++r) rp[mt][r] = 0.f;
#pragma unroll
    for (int nt = 0; nt < 4; ++nt) cp[nt] = 0.f;

#pragma unroll
    for (int mt = 0; mt < 4; ++mt)
#pragma unroll
        for (int nt = 0; nt < 4; ++nt)
#pragma unroll
            for (int r = 0; r < 4; ++r) {
                const float e = __expf(acc[mt][nt][r]);   // S in [-1,1]: no max needed
                rp[mt][r] += e;
                cp[nt]    += e;
            }

    // Row sums: reduce across the 16 col-lanes (low 4 lane bits).
#pragma unroll
    for (int mt = 0; mt < 4; ++mt)
#pragma unroll
        for (int r = 0; r < 4; ++r) {
            float v = rp[mt][r];
            v += __shfl_xor(v, 1);
            v += __shfl_xor(v, 2);
            v += __shfl_xor(v, 4);
            v += __shfl_xor(v, 8);
            rp[mt][r] = v;
        }
    if (l16 == 0) {
#pragma unroll
        for (int mt = 0; mt < 4; ++mt)
#pragma unroll
            for (int r = 0; r < 4; ++r)
                atomicAdd(&rowsum[rowBase + wr * 64 + mt * 16 + quad * 4 + r], rp[mt][r]);
    }
    // Col sums: reduce across the 4 quads (lane bits 4,5).
#pragma unroll
    for (int nt = 0; nt < 4; ++nt) {
        float v = cp[nt];
        v += __shfl_xor(v, 16);
        v += __shfl_xor(v, 32);
        if (quad == 0)
            atomicAdd(&colsum[colBase + wc * 64 + nt * 16 + l16], v);
    }
}

__global__ __launch_bounds__(256) void finalize_kernel(
    const float* __restrict__ rowsum, const float* __restrict__ colsum,
    const float* __restrict__ sim, float* __restrict__ out) {
    const int tid = threadIdx.x;
    float acc = 0.f;
    for (int i = tid; i < BS; i += 256)
        acc += logf(rowsum[i]) + logf(colsum[i]) - 2.f * sim[i];
#pragma unroll
    for (int off = 1; off < 64; off <<= 1) acc += __shfl_xor(acc, off);
    __shared__ float red[4];
    const int wave = tid >> 6, lane = tid & 63;
    if (lane == 0) red[wave] = acc;
    __syncthreads();
    if (tid == 0) out[0] = (red[0] + red[1] + red[2] + red[3]) / (float)BS;
}

extern "C" void kernel_launch(void* const* d_in, const int* in_sizes, int n_in,
                              void* d_out, int out_size, void* d_ws, size_t ws_size,
                              hipStream_t stream) {
    const float* text = (const float*)d_in[0];
    const float* ctr  = (const float*)d_in[1];

    char* ws = (char*)d_ws;
    const size_t embBytes = (size_t)BS * DIM * sizeof(__hip_bfloat16);  // 12,582,912
    __hip_bfloat16* tb = (__hip_bfloat16*)ws;
    __hip_bfloat16* cb = (__hip_bfloat16*)(ws + embBytes);
    float* sim    = (float*)(ws + 2 * embBytes);
    float* rowsum = (float*)(ws + 2 * embBytes + BS * sizeof(float));
    float* colsum = (float*)(ws + 2 * embBytes + 2 * BS * sizeof(float));

    hipMemsetAsync(rowsum, 0, 2 * BS * sizeof(float), stream);  // ws is poisoned 0xAA

    normalize_kernel<<<BS, 256, 0, stream>>>(text, ctr, tb, cb, sim);

    dim3 grid(BS / TILE, BS / TILE);
    gemm_lse_kernel<<<grid, 256, 0, stream>>>(tb, cb, rowsum, colsum);

    finalize_kernel<<<1, 256, 0, stream>>>(rowsum, colsum, sim, (float*)d_out);
}

// Round 2
// 237.171 us; speedup vs baseline: 1.2472x; 1.2472x over previous
//
#include <hip/hip_runtime.h>
#include <hip/hip_bf16.h>

#define BS   8192
#define DIM  768
#define TILE 128
#define BK   64

typedef float f32x4 __attribute__((ext_vector_type(4)));

__device__ __forceinline__ void async16(const void* g, void* l) {
    __builtin_amdgcn_global_load_lds(
        (const __attribute__((address_space(1))) unsigned int*)g,
        (__attribute__((address_space(3))) unsigned int*)l,
        16, 0, 0);
}

// One wave per row: L2-norm both embeddings, emit fp8 e4m3, diag sim in fp32.
__global__ __launch_bounds__(256) void normalize_kernel(
    const float* __restrict__ text, const float* __restrict__ ctr,
    unsigned char* __restrict__ tq, unsigned char* __restrict__ cq,
    float* __restrict__ sim) {
    const int lane = threadIdx.x & 63;
    const int row  = blockIdx.x * 4 + (threadIdx.x >> 6);
    const size_t base = (size_t)row * DIM;

    float4 t[3], c[3];
    float st = 0.f, sc = 0.f, sd = 0.f;
#pragma unroll
    for (int i = 0; i < 3; ++i) {
        t[i] = *(const float4*)&text[base + lane * 4 + i * 256];
        c[i] = *(const float4*)&ctr [base + lane * 4 + i * 256];
        st += t[i].x*t[i].x + t[i].y*t[i].y + t[i].z*t[i].z + t[i].w*t[i].w;
        sc += c[i].x*c[i].x + c[i].y*c[i].y + c[i].z*c[i].z + c[i].w*c[i].w;
        sd += t[i].x*c[i].x + t[i].y*c[i].y + t[i].z*c[i].z + t[i].w*c[i].w;
    }
#pragma unroll
    for (int off = 1; off < 64; off <<= 1) {
        st += __shfl_xor(st, off);
        sc += __shfl_xor(sc, off);
        sd += __shfl_xor(sd, off);
    }
    const float invt = 1.0f / fmaxf(sqrtf(st), 1e-8f);
    const float invc = 1.0f / fmaxf(sqrtf(sc), 1e-8f);
#pragma unroll
    for (int i = 0; i < 3; ++i) {
        unsigned int wt = (unsigned int)__builtin_amdgcn_cvt_pk_fp8_f32(t[i].x * invt, t[i].y * invt, 0, false);
        wt = (unsigned int)__builtin_amdgcn_cvt_pk_fp8_f32(t[i].z * invt, t[i].w * invt, (int)wt, true);
        unsigned int wcq = (unsigned int)__builtin_amdgcn_cvt_pk_fp8_f32(c[i].x * invc, c[i].y * invc, 0, false);
        wcq = (unsigned int)__builtin_amdgcn_cvt_pk_fp8_f32(c[i].z * invc, c[i].w * invc, (int)wcq, true);
        *(unsigned int*)&tq[base + lane * 4 + i * 256] = wt;
        *(unsigned int*)&cq[base + lane * 4 + i * 256] = wcq;
    }
    if (lane == 0) sim[row] = sd * invt * invc;
}

// fp8 GEMM: 128x128 tile, BK=64, 16x16x32 fp8 MFMA, XOR-swizzled LDS,
// XCD-banded block swizzle. Epilogue: exp + reduce into rowsum/colsum.
__global__ __launch_bounds__(256) void gemm_lse_kernel(
    const unsigned char* __restrict__ tq, const unsigned char* __restrict__ cq,
    float* __restrict__ rowsum, float* __restrict__ colsum) {
    __shared__ long ldsA8[TILE * BK / 8];   // 8 KB
    __shared__ long ldsB8[TILE * BK / 8];   // 8 KB
    char* ldsA = (char*)ldsA8;
    char* ldsB = (char*)ldsB8;

    const int tid = threadIdx.x;

    // XCD-banded swizzle: XCD x owns tile-rows [8x, 8x+8), sweeping columns.
    const int bid = blockIdx.x;
    const int xcd = bid & 7, idx = bid >> 3;
    const int tileCol = idx >> 3, rowInBand = idx & 7;
    const int rowBase = (xcd * 8 + rowInBand) * TILE;
    const int colBase = tileCol * TILE;

    const int wave = tid >> 6, lane = tid & 63;
    const int wr = wave >> 1, wc = wave & 1;
    const int quad = lane >> 4, l16 = lane & 15;

    // Staging: 512 16B chunks per tile; thread does chunks tid, tid+256.
    // chunk c -> row c>>2, phys col-chunk c&3; logical chunk = phys ^ (row&3).
    const int c0 = tid, c1 = tid + 256;
    const int r0 = c0 >> 2, l0 = (c0 & 3) ^ (r0 & 3);
    const int r1 = c1 >> 2, l1 = (c1 & 3) ^ (r1 & 3);
    const unsigned char* ga0 = tq + (size_t)(rowBase + r0) * DIM + l0 * 16;
    const unsigned char* ga1 = tq + (size_t)(rowBase + r1) * DIM + l1 * 16;
    const unsigned char* gb0 = cq + (size_t)(colBase + r0) * DIM + l0 * 16;
    const unsigned char* gb1 = cq + (size_t)(colBase + r1) * DIM + l1 * 16;
    char* dA0 = ldsA + c0 * 16; char* dA1 = ldsA + c1 * 16;
    char* dB0 = ldsB + c0 * 16; char* dB1 = ldsB + c1 * 16;

    // Fragment read addressing (phys = row*64 + (logChunk ^ (row&3))*16 + half*8)
    int aoff[4], boff[4], koff[2];
#pragma unroll
    for (int mt = 0; mt < 4; ++mt) aoff[mt] = (wr * 64 + mt * 16 + l16) * BK;
#pragma unroll
    for (int nt = 0; nt < 4; ++nt) boff[nt] = (wc * 64 + nt * 16 + l16) * BK;
#pragma unroll
    for (int kc = 0; kc < 2; ++kc)
        koff[kc] = (((kc * 2 + (quad >> 1)) ^ (l16 & 3)) << 4) + (quad & 1) * 8;

    f32x4 acc[4][4];
#pragma unroll
    for (int mt = 0; mt < 4; ++mt)
#pragma unroll
        for (int nt = 0; nt < 4; ++nt)
            acc[mt][nt] = (f32x4){0.f, 0.f, 0.f, 0.f};

    for (int k0 = 0; k0 < DIM; k0 += BK) {
        async16(ga0 + k0, dA0);
        async16(ga1 + k0, dA1);
        async16(gb0 + k0, dB0);
        async16(gb1 + k0, dB1);
        __syncthreads();

        long af[4][2], bf[4][2];
#pragma unroll
        for (int mt = 0; mt < 4; ++mt)
#pragma unroll
            for (int kc = 0; kc < 2; ++kc)
                af[mt][kc] = *(const long*)(ldsA + aoff[mt] + koff[kc]);
#pragma unroll
        for (int nt = 0; nt < 4; ++nt)
#pragma unroll
            for (int kc = 0; kc < 2; ++kc)
                bf[nt][kc] = *(const long*)(ldsB + boff[nt] + koff[kc]);

#pragma unroll
        for (int mt = 0; mt < 4; ++mt)
#pragma unroll
            for (int nt = 0; nt < 4; ++nt)
#pragma unroll
                for (int kc = 0; kc < 2; ++kc)
                    acc[mt][nt] = __builtin_amdgcn_mfma_f32_16x16x32_fp8_fp8(
                        af[mt][kc], bf[nt][kc], acc[mt][nt], 0, 0, 0);
        __syncthreads();
    }

    // Epilogue. D layout: col = l16 (ctr idx), row = quad*4 + reg (text idx).
    float rp[4][4];
    float cp[4];
#pragma unroll
    for (int mt = 0; mt < 4; ++mt)
#pragma unroll
        for (int r = 0; r < 4; ++r) rp[mt][r] = 0.f;
#pragma unroll
    for (int nt = 0; nt < 4; ++nt) cp[nt] = 0.f;

#pragma unroll
    for (int mt = 0; mt < 4; ++mt)
#pragma unroll
        for (int nt = 0; nt < 4; ++nt)
#pragma unroll
            for (int r = 0; r < 4; ++r) {
                const float e = __expf(acc[mt][nt][r]);   // S in [-1,1]: no max needed
                rp[mt][r] += e;
                cp[nt]    += e;
            }

#pragma unroll
    for (int mt = 0; mt < 4; ++mt)
#pragma unroll
        for (int r = 0; r < 4; ++r) {
            float v = rp[mt][r];
            v += __shfl_xor(v, 1);
            v += __shfl_xor(v, 2);
            v += __shfl_xor(v, 4);
            v += __shfl_xor(v, 8);
            rp[mt][r] = v;
        }
    if (l16 == 0) {
#pragma unroll
        for (int mt = 0; mt < 4; ++mt)
#pragma unroll
            for (int r = 0; r < 4; ++r)
                atomicAdd(&rowsum[rowBase + wr * 64 + mt * 16 + quad * 4 + r], rp[mt][r]);
    }
#pragma unroll
    for (int nt = 0; nt < 4; ++nt) {
        float v = cp[nt];
        v += __shfl_xor(v, 16);
        v += __shfl_xor(v, 32);
        if (quad == 0)
            atomicAdd(&colsum[colBase + wc * 64 + nt * 16 + l16], v);
    }
}

__global__ __launch_bounds__(256) void finalize_kernel(
    const float* __restrict__ rowsum, const float* __restrict__ colsum,
    const float* __restrict__ sim, float* __restrict__ out) {
    const int tid = threadIdx.x;
    float acc = 0.f;
    for (int i = tid; i < BS; i += 256)
        acc += logf(rowsum[i]) + logf(colsum[i]) - 2.f * sim[i];
#pragma unroll
    for (int off = 1; off < 64; off <<= 1) acc += __shfl_xor(acc, off);
    __shared__ float red[4];
    const int wave = tid >> 6, lane = tid & 63;
    if (lane == 0) red[wave] = acc;
    __syncthreads();
    if (tid == 0) out[0] = (red[0] + red[1] + red[2] + red[3]) / (float)BS;
}

extern "C" void kernel_launch(void* const* d_in, const int* in_sizes, int n_in,
                              void* d_out, int out_size, void* d_ws, size_t ws_size,
                              hipStream_t stream) {
    const float* text = (const float*)d_in[0];
    const float* ctr  = (const float*)d_in[1];

    char* ws = (char*)d_ws;
    const size_t embBytes = (size_t)BS * DIM;   // fp8: 6,291,456 bytes each
    unsigned char* tq = (unsigned char*)ws;
    unsigned char* cq = (unsigned char*)(ws + embBytes);
    float* sim    = (float*)(ws + 2 * embBytes);
    float* rowsum = (float*)(ws + 2 * embBytes + BS * sizeof(float));
    float* colsum = (float*)(ws + 2 * embBytes + 2 * BS * sizeof(float));

    hipMemsetAsync(rowsum, 0, 2 * BS * sizeof(float), stream);  // ws poisoned 0xAA

    normalize_kernel<<<BS / 4, 256, 0, stream>>>(text, ctr, tq, cq, sim);

    gemm_lse_kernel<<<(BS / TILE) * (BS / TILE), 256, 0, stream>>>(tq, cq, rowsum, colsum);

    finalize_kernel<<<1, 256, 0, stream>>>(rowsum, colsum, sim, (float*)d_out);
}

// Round 3
// 204.851 us; speedup vs baseline: 1.4440x; 1.1578x over previous
//
#include <hip/hip_runtime.h>
#include <hip/hip_bf16.h>

#define BS   8192
#define DIM  768
#define TILE 128
#define BK   128   // one scaled-MFMA K per iteration; 6 iterations total

typedef float f32x4 __attribute__((ext_vector_type(4)));
typedef int   i32x4 __attribute__((ext_vector_type(4)));
typedef int   i32x8 __attribute__((ext_vector_type(8)));

__device__ __forceinline__ void async16(const void* g, void* l) {
    __builtin_amdgcn_global_load_lds(
        (const __attribute__((address_space(1))) unsigned int*)g,
        (__attribute__((address_space(3))) unsigned int*)l,
        16, 0, 0);
}

// One wave per row: L2-norm both embeddings, emit fp8 e4m3, diag sim in fp32.
__global__ __launch_bounds__(256) void normalize_kernel(
    const float* __restrict__ text, const float* __restrict__ ctr,
    unsigned char* __restrict__ tq, unsigned char* __restrict__ cq,
    float* __restrict__ sim) {
    const int lane = threadIdx.x & 63;
    const int row  = blockIdx.x * 4 + (threadIdx.x >> 6);
    const size_t base = (size_t)row * DIM;

    float4 t[3], c[3];
    float st = 0.f, sc = 0.f, sd = 0.f;
#pragma unroll
    for (int i = 0; i < 3; ++i) {
        t[i] = *(const float4*)&text[base + lane * 4 + i * 256];
        c[i] = *(const float4*)&ctr [base + lane * 4 + i * 256];
        st += t[i].x*t[i].x + t[i].y*t[i].y + t[i].z*t[i].z + t[i].w*t[i].w;
        sc += c[i].x*c[i].x + c[i].y*c[i].y + c[i].z*c[i].z + c[i].w*c[i].w;
        sd += t[i].x*c[i].x + t[i].y*c[i].y + t[i].z*c[i].z + t[i].w*c[i].w;
    }
#pragma unroll
    for (int off = 1; off < 64; off <<= 1) {
        st += __shfl_xor(st, off);
        sc += __shfl_xor(sc, off);
        sd += __shfl_xor(sd, off);
    }
    const float invt = 1.0f / fmaxf(sqrtf(st), 1e-8f);
    const float invc = 1.0f / fmaxf(sqrtf(sc), 1e-8f);
#pragma unroll
    for (int i = 0; i < 3; ++i) {
        unsigned int wt = (unsigned int)__builtin_amdgcn_cvt_pk_fp8_f32(t[i].x * invt, t[i].y * invt, 0, false);
        wt = (unsigned int)__builtin_amdgcn_cvt_pk_fp8_f32(t[i].z * invt, t[i].w * invt, (int)wt, true);
        unsigned int wcq = (unsigned int)__builtin_amdgcn_cvt_pk_fp8_f32(c[i].x * invc, c[i].y * invc, 0, false);
        wcq = (unsigned int)__builtin_amdgcn_cvt_pk_fp8_f32(c[i].z * invc, c[i].w * invc, (int)wcq, true);
        *(unsigned int*)&tq[base + lane * 4 + i * 256] = wt;
        *(unsigned int*)&cq[base + lane * 4 + i * 256] = wcq;
    }
    if (lane == 0) sim[row] = sd * invt * invc;
}

// MX-scaled fp8 GEMM (unit scales): 128x128 tile, BK=128,
// mfma_scale_f32_16x16x128_f8f6f4 at ~2x the non-scaled fp8 rate.
// LDS layout: [kc(4)][row(128)][32B], halves swizzled by (kc&1) so each
// wave-wide ds_read_b128 hits all 32 banks uniformly (8 dwords/bank floor).
__global__ __launch_bounds__(256) void gemm_lse_kernel(
    const unsigned char* __restrict__ tq, const unsigned char* __restrict__ cq,
    float* __restrict__ rowsum, float* __restrict__ colsum) {
    __shared__ char ldsA[TILE * BK];   // 16 KB
    __shared__ char ldsB[TILE * BK];   // 16 KB

    const int tid = threadIdx.x;

    // XCD-banded swizzle: XCD x owns tile-rows [8x, 8x+8), sweeping columns.
    const int bid = blockIdx.x;
    const int xcd = bid & 7, idx = bid >> 3;
    const int tileCol = idx >> 3, rowInBand = idx & 7;
    const int rowBase = (xcd * 8 + rowInBand) * TILE;
    const int colBase = tileCol * TILE;

    const int wave = tid >> 6, lane = tid & 63;
    const int wr = wave >> 1, wc = wave & 1;
    const int quad = lane >> 4, l16 = lane & 15;

    // Staging: 1024 16B chunks per tile; thread owns chunks tid + i*256.
    // chunk p -> kc = p>>8, row = (p>>1)&127, phys-half = p&1,
    // logical-half = (p&1) ^ (kc&1). LDS dest is linear (wave-uniform+lane*16).
    int goff[4];
    char *dstA[4], *dstB[4];
#pragma unroll
    for (int i = 0; i < 4; ++i) {
        const int p  = tid + i * 256;
        const int kc = p >> 8;
        const int row = (p >> 1) & 127;
        const int hl  = (p & 1) ^ (kc & 1);
        goff[i] = row * DIM + kc * 32 + hl * 16;
        dstA[i] = ldsA + p * 16;
        dstB[i] = ldsB + p * 16;
    }
    const unsigned char* gA = tq + (size_t)rowBase * DIM;
    const unsigned char* gB = cq + (size_t)colBase * DIM;

    // Fragment addressing: lane (quad,l16) needs k-block kc=quad of its row;
    // physical half = logical half ^ (quad&1).
    const int sw = quad & 1;
    int aoff[4], boff[4];
#pragma unroll
    for (int mt = 0; mt < 4; ++mt) aoff[mt] = quad * 4096 + (wr * 64 + mt * 16 + l16) * 32;
#pragma unroll
    for (int nt = 0; nt < 4; ++nt) boff[nt] = quad * 4096 + (wc * 64 + nt * 16 + l16) * 32;

    f32x4 acc[4][4];
#pragma unroll
    for (int mt = 0; mt < 4; ++mt)
#pragma unroll
        for (int nt = 0; nt < 4; ++nt)
            acc[mt][nt] = (f32x4){0.f, 0.f, 0.f, 0.f};

    for (int k0 = 0; k0 < DIM; k0 += BK) {
#pragma unroll
        for (int i = 0; i < 4; ++i) {
            async16(gA + goff[i] + k0, dstA[i]);
            async16(gB + goff[i] + k0, dstB[i]);
        }
        __syncthreads();

        i32x8 af[4], bf[4];
#pragma unroll
        for (int mt = 0; mt < 4; ++mt) {
            i32x4 lo = *(const i32x4*)(ldsA + aoff[mt] + sw * 16);
            i32x4 hi = *(const i32x4*)(ldsA + aoff[mt] + (sw ^ 1) * 16);
            af[mt] = __builtin_shufflevector(lo, hi, 0, 1, 2, 3, 4, 5, 6, 7);
        }
#pragma unroll
        for (int nt = 0; nt < 4; ++nt) {
            i32x4 lo = *(const i32x4*)(ldsB + boff[nt] + sw * 16);
            i32x4 hi = *(const i32x4*)(ldsB + boff[nt] + (sw ^ 1) * 16);
            bf[nt] = __builtin_shufflevector(lo, hi, 0, 1, 2, 3, 4, 5, 6, 7);
        }

#pragma unroll
        for (int mt = 0; mt < 4; ++mt)
#pragma unroll
            for (int nt = 0; nt < 4; ++nt)
                acc[mt][nt] = __builtin_amdgcn_mfma_scale_f32_16x16x128_f8f6f4(
                    af[mt], bf[nt], acc[mt][nt], 0, 0, 0, 127, 0, 127);
        __syncthreads();
    }

    // Epilogue. D layout: col = l16 (ctr idx), row = quad*4 + reg (text idx).
    float rp[4][4];
    float cp[4];
#pragma unroll
    for (int mt = 0; mt < 4; ++mt)
#pragma unroll
        for (int r = 0; r < 4; ++r) rp[mt][r] = 0.f;
#pragma unroll
    for (int nt = 0; nt < 4; ++nt) cp[nt] = 0.f;

#pragma unroll
    for (int mt = 0; mt < 4; ++mt)
#pragma unroll
        for (int nt = 0; nt < 4; ++nt)
#pragma unroll
            for (int r = 0; r < 4; ++r) {
                const float e = __expf(acc[mt][nt][r]);   // S in [-1,1]: no max needed
                rp[mt][r] += e;
                cp[nt]    += e;
            }

#pragma unroll
    for (int mt = 0; mt < 4; ++mt)
#pragma unroll
        for (int r = 0; r < 4; ++r) {
            float v = rp[mt][r];
            v += __shfl_xor(v, 1);
            v += __shfl_xor(v, 2);
            v += __shfl_xor(v, 4);
            v += __shfl_xor(v, 8);
            rp[mt][r] = v;
        }
    if (l16 == 0) {
#pragma unroll
        for (int mt = 0; mt < 4; ++mt)
#pragma unroll
            for (int r = 0; r < 4; ++r)
                atomicAdd(&rowsum[rowBase + wr * 64 + mt * 16 + quad * 4 + r], rp[mt][r]);
    }
#pragma unroll
    for (int nt = 0; nt < 4; ++nt) {
        float v = cp[nt];
        v += __shfl_xor(v, 16);
        v += __shfl_xor(v, 32);
        if (quad == 0)
            atomicAdd(&colsum[colBase + wc * 64 + nt * 16 + l16], v);
    }
}

__global__ __launch_bounds__(256) void finalize_kernel(
    const float* __restrict__ rowsum, const float* __restrict__ colsum,
    const float* __restrict__ sim, float* __restrict__ out) {
    const int tid = threadIdx.x;
    float acc = 0.f;
    for (int i = tid; i < BS; i += 256)
        acc += logf(rowsum[i]) + logf(colsum[i]) - 2.f * sim[i];
#pragma unroll
    for (int off = 1; off < 64; off <<= 1) acc += __shfl_xor(acc, off);
    __shared__ float red[4];
    const int wave = tid >> 6, lane = tid & 63;
    if (lane == 0) red[wave] = acc;
    __syncthreads();
    if (tid == 0) out[0] = (red[0] + red[1] + red[2] + red[3]) / (float)BS;
}

extern "C" void kernel_launch(void* const* d_in, const int* in_sizes, int n_in,
                              void* d_out, int out_size, void* d_ws, size_t ws_size,
                              hipStream_t stream) {
    const float* text = (const float*)d_in[0];
    const float* ctr  = (const float*)d_in[1];

    char* ws = (char*)d_ws;
    const size_t embBytes = (size_t)BS * DIM;   // fp8: 6,291,456 bytes each
    unsigned char* tq = (unsigned char*)ws;
    unsigned char* cq = (unsigned char*)(ws + embBytes);
    float* sim    = (float*)(ws + 2 * embBytes);
    float* rowsum = (float*)(ws + 2 * embBytes + BS * sizeof(float));
    float* colsum = (float*)(ws + 2 * embBytes + 2 * BS * sizeof(float));

    hipMemsetAsync(rowsum, 0, 2 * BS * sizeof(float), stream);  // ws poisoned 0xAA

    normalize_kernel<<<BS / 4, 256, 0, stream>>>(text, ctr, tq, cq, sim);

    gemm_lse_kernel<<<(BS / TILE) * (BS / TILE), 256, 0, stream>>>(tq, cq, rowsum, colsum);

    finalize_kernel<<<1, 256, 0, stream>>>(rowsum, colsum, sim, (float*)d_out);
}

// Round 4
// 195.770 us; speedup vs baseline: 1.5109x; 1.0464x over previous
//
#include <hip/hip_runtime.h>
#include <hip/hip_bf16.h>

#define BS   8192
#define DIM  768
#define TILE 128
#define BK   128   // one scaled-MFMA K per iteration; 6 iterations total

typedef float f32x4 __attribute__((ext_vector_type(4)));
typedef int   i32x4 __attribute__((ext_vector_type(4)));
typedef int   i32x8 __attribute__((ext_vector_type(8)));

__device__ __forceinline__ void async16(const void* g, void* l) {
    __builtin_amdgcn_global_load_lds(
        (const __attribute__((address_space(1))) unsigned int*)g,
        (__attribute__((address_space(3))) unsigned int*)l,
        16, 0, 0);
}

// One wave per row: L2-norm both embeddings, emit fp8 e4m3, diag sim in fp32.
// Blocks 0..63 also zero rowsum/colsum (replaces the hipMemsetAsync dispatch).
__global__ __launch_bounds__(256) void normalize_kernel(
    const float* __restrict__ text, const float* __restrict__ ctr,
    unsigned char* __restrict__ tq, unsigned char* __restrict__ cq,
    float* __restrict__ sim, float* __restrict__ rowsum, float* __restrict__ colsum) {
    if (blockIdx.x < 64) {
        const int i = blockIdx.x * 256 + threadIdx.x;   // covers 16384 = 2*BS
        rowsum[i] = 0.f;
        colsum[i] = 0.f;
    }
    const int lane = threadIdx.x & 63;
    const int row  = blockIdx.x * 4 + (threadIdx.x >> 6);
    const size_t base = (size_t)row * DIM;

    float4 t[3], c[3];
    float st = 0.f, sc = 0.f, sd = 0.f;
#pragma unroll
    for (int i = 0; i < 3; ++i) {
        t[i] = *(const float4*)&text[base + lane * 4 + i * 256];
        c[i] = *(const float4*)&ctr [base + lane * 4 + i * 256];
        st += t[i].x*t[i].x + t[i].y*t[i].y + t[i].z*t[i].z + t[i].w*t[i].w;
        sc += c[i].x*c[i].x + c[i].y*c[i].y + c[i].z*c[i].z + c[i].w*c[i].w;
        sd += t[i].x*c[i].x + t[i].y*c[i].y + t[i].z*c[i].z + t[i].w*c[i].w;
    }
#pragma unroll
    for (int off = 1; off < 64; off <<= 1) {
        st += __shfl_xor(st, off);
        sc += __shfl_xor(sc, off);
        sd += __shfl_xor(sd, off);
    }
    const float invt = 1.0f / fmaxf(sqrtf(st), 1e-8f);
    const float invc = 1.0f / fmaxf(sqrtf(sc), 1e-8f);
#pragma unroll
    for (int i = 0; i < 3; ++i) {
        unsigned int wt = (unsigned int)__builtin_amdgcn_cvt_pk_fp8_f32(t[i].x * invt, t[i].y * invt, 0, false);
        wt = (unsigned int)__builtin_amdgcn_cvt_pk_fp8_f32(t[i].z * invt, t[i].w * invt, (int)wt, true);
        unsigned int wcq = (unsigned int)__builtin_amdgcn_cvt_pk_fp8_f32(c[i].x * invc, c[i].y * invc, 0, false);
        wcq = (unsigned int)__builtin_amdgcn_cvt_pk_fp8_f32(c[i].z * invc, c[i].w * invc, (int)wcq, true);
        *(unsigned int*)&tq[base + lane * 4 + i * 256] = wt;
        *(unsigned int*)&cq[base + lane * 4 + i * 256] = wcq;
    }
    if (lane == 0) sim[row] = sd * invt * invc;
}

// MX-scaled fp8 GEMM (unit scales): 128x128 tile, BK=128, 512 threads / 8 waves
// in a 2x4 grid (64x32 output per wave -> acc=32 regs, total ~110 < 128 so the
// register file allows 4 waves/SIMD; rounds 1-3 were silently capped at 2).
// LDS layout: [kc(4)][row(128)][32B], halves swizzled by (kc&1): conflict-free
// (verified: SQ_LDS_BANK_CONFLICT = 0 in round 3).
__global__ __launch_bounds__(512, 4) void gemm_lse_kernel(
    const unsigned char* __restrict__ tq, const unsigned char* __restrict__ cq,
    float* __restrict__ rowsum, float* __restrict__ colsum) {
    __shared__ char ldsA[TILE * BK];   // 16 KB
    __shared__ char ldsB[TILE * BK];   // 16 KB

    const int tid = threadIdx.x;

    // XCD-banded swizzle: XCD x owns tile-rows [8x, 8x+8), sweeping columns.
    const int bid = blockIdx.x;
    const int xcd = bid & 7, idx = bid >> 3;
    const int tileCol = idx >> 3, rowInBand = idx & 7;
    const int rowBase = (xcd * 8 + rowInBand) * TILE;
    const int colBase = tileCol * TILE;

    const int wave = tid >> 6, lane = tid & 63;
    const int wr = wave >> 2, wc = wave & 3;        // 2x4 wave grid: 64 rows x 32 cols
    const int quad = lane >> 4, l16 = lane & 15;

    // Staging: 1024 16B chunks per tile; thread owns chunks tid, tid+512.
    // chunk p -> kc = p>>8, row = (p>>1)&127, phys-half = p&1,
    // logical-half = (p&1) ^ (kc&1). LDS dest is linear (wave-uniform+lane*16).
    int goff[2];
    char *dstA[2], *dstB[2];
#pragma unroll
    for (int i = 0; i < 2; ++i) {
        const int p  = tid + i * 512;
        const int kc = p >> 8;
        const int row = (p >> 1) & 127;
        const int hl  = (p & 1) ^ (kc & 1);
        goff[i] = row * DIM + kc * 32 + hl * 16;
        dstA[i] = ldsA + p * 16;
        dstB[i] = ldsB + p * 16;
    }
    const unsigned char* gA = tq + (size_t)rowBase * DIM;
    const unsigned char* gB = cq + (size_t)colBase * DIM;

    // Fragment addressing: lane (quad,l16) needs k-block kc=quad of its row;
    // physical half = logical half ^ (quad&1).
    const int sw = quad & 1;
    int aoff[4], boff[2];
#pragma unroll
    for (int mt = 0; mt < 4; ++mt) aoff[mt] = quad * 4096 + (wr * 64 + mt * 16 + l16) * 32;
#pragma unroll
    for (int nt = 0; nt < 2; ++nt) boff[nt] = quad * 4096 + (wc * 32 + nt * 16 + l16) * 32;

    f32x4 acc[4][2];
#pragma unroll
    for (int mt = 0; mt < 4; ++mt)
#pragma unroll
        for (int nt = 0; nt < 2; ++nt)
            acc[mt][nt] = (f32x4){0.f, 0.f, 0.f, 0.f};

    for (int k0 = 0; k0 < DIM; k0 += BK) {
#pragma unroll
        for (int i = 0; i < 2; ++i) {
            async16(gA + goff[i] + k0, dstA[i]);
            async16(gB + goff[i] + k0, dstB[i]);
        }
        __syncthreads();

        i32x8 bf[2];
#pragma unroll
        for (int nt = 0; nt < 2; ++nt) {
            i32x4 lo = *(const i32x4*)(ldsB + boff[nt] + sw * 16);
            i32x4 hi = *(const i32x4*)(ldsB + boff[nt] + (sw ^ 1) * 16);
            bf[nt] = __builtin_shufflevector(lo, hi, 0, 1, 2, 3, 4, 5, 6, 7);
        }
#pragma unroll
        for (int mt = 0; mt < 4; ++mt) {
            i32x4 lo = *(const i32x4*)(ldsA + aoff[mt] + sw * 16);
            i32x4 hi = *(const i32x4*)(ldsA + aoff[mt] + (sw ^ 1) * 16);
            i32x8 af = __builtin_shufflevector(lo, hi, 0, 1, 2, 3, 4, 5, 6, 7);
#pragma unroll
            for (int nt = 0; nt < 2; ++nt)
                acc[mt][nt] = __builtin_amdgcn_mfma_scale_f32_16x16x128_f8f6f4(
                    af, bf[nt], acc[mt][nt], 0, 0, 0, 127, 0, 127);
        }
        __syncthreads();
    }

    // Epilogue. D layout: col = l16 (ctr idx), row = quad*4 + reg (text idx).
    float rp[4][4];   // [mt][reg] partials over this wave's 32 cols
    float cp[2];      // [nt] partials over this wave's 64 rows
#pragma unroll
    for (int mt = 0; mt < 4; ++mt)
#pragma unroll
        for (int r = 0; r < 4; ++r) rp[mt][r] = 0.f;
#pragma unroll
    for (int nt = 0; nt < 2; ++nt) cp[nt] = 0.f;

#pragma unroll
    for (int mt = 0; mt < 4; ++mt)
#pragma unroll
        for (int nt = 0; nt < 2; ++nt)
#pragma unroll
            for (int r = 0; r < 4; ++r) {
                const float e = __expf(acc[mt][nt][r]);   // S in [-1,1]: no max needed
                rp[mt][r] += e;
                cp[nt]    += e;
            }

#pragma unroll
    for (int mt = 0; mt < 4; ++mt)
#pragma unroll
        for (int r = 0; r < 4; ++r) {
            float v = rp[mt][r];
            v += __shfl_xor(v, 1);
            v += __shfl_xor(v, 2);
            v += __shfl_xor(v, 4);
            v += __shfl_xor(v, 8);
            rp[mt][r] = v;
        }
    if (l16 == 0) {
#pragma unroll
        for (int mt = 0; mt < 4; ++mt)
#pragma unroll
            for (int r = 0; r < 4; ++r)
                atomicAdd(&rowsum[rowBase + wr * 64 + mt * 16 + quad * 4 + r], rp[mt][r]);
    }
#pragma unroll
    for (int nt = 0; nt < 2; ++nt) {
        float v = cp[nt];
        v += __shfl_xor(v, 16);
        v += __shfl_xor(v, 32);
        if (quad == 0)
            atomicAdd(&colsum[colBase + wc * 32 + nt * 16 + l16], v);
    }
}

__global__ __launch_bounds__(1024) void finalize_kernel(
    const float* __restrict__ rowsum, const float* __restrict__ colsum,
    const float* __restrict__ sim, float* __restrict__ out) {
    const int tid = threadIdx.x;
    float acc = 0.f;
#pragma unroll
    for (int i = 0; i < 2; ++i) {
        const int j = (tid + i * 1024) * 4;
        float4 rs = *(const float4*)&rowsum[j];
        float4 cs = *(const float4*)&colsum[j];
        float4 sm = *(const float4*)&sim[j];
        acc += __logf(rs.x) + __logf(rs.y) + __logf(rs.z) + __logf(rs.w);
        acc += __logf(cs.x) + __logf(cs.y) + __logf(cs.z) + __logf(cs.w);
        acc -= 2.f * (sm.x + sm.y + sm.z + sm.w);
    }
#pragma unroll
    for (int off = 1; off < 64; off <<= 1) acc += __shfl_xor(acc, off);
    __shared__ float red[16];
    const int wave = tid >> 6, lane = tid & 63;
    if (lane == 0) red[wave] = acc;
    __syncthreads();
    if (tid == 0) {
        float s = 0.f;
#pragma unroll
        for (int w = 0; w < 16; ++w) s += red[w];
        out[0] = s / (float)BS;
    }
}

extern "C" void kernel_launch(void* const* d_in, const int* in_sizes, int n_in,
                              void* d_out, int out_size, void* d_ws, size_t ws_size,
                              hipStream_t stream) {
    const float* text = (const float*)d_in[0];
    const float* ctr  = (const float*)d_in[1];

    char* ws = (char*)d_ws;
    const size_t embBytes = (size_t)BS * DIM;   // fp8: 6,291,456 bytes each
    unsigned char* tq = (unsigned char*)ws;
    unsigned char* cq = (unsigned char*)(ws + embBytes);
    float* sim    = (float*)(ws + 2 * embBytes);
    float* rowsum = (float*)(ws + 2 * embBytes + BS * sizeof(float));
    float* colsum = (float*)(ws + 2 * embBytes + 2 * BS * sizeof(float));

    normalize_kernel<<<BS / 4, 256, 0, stream>>>(text, ctr, tq, cq, sim, rowsum, colsum);

    gemm_lse_kernel<<<(BS / TILE) * (BS / TILE), 512, 0, stream>>>(tq, cq, rowsum, colsum);

    finalize_kernel<<<1, 1024, 0, stream>>>(rowsum, colsum, sim, (float*)d_out);
}